// Round 2
// baseline (491.153 us; speedup 1.0000x reference)
//
#include <hip/hip_runtime.h>

// VQ-VAE VectorQuantizer forward, fp32, MI355X.
// B=64, C=D=64, H=W=32 -> N=65536 pixels, K=1024 codes.
// Outputs (flat concat): [0] loss, [1..4194305) quantized BCHW, [4194305..) indices (as float)
//
// R1: K-split argmin — 8 waves/block, each wave owns a 128-code chunk for the
// block's 64 pixels. Per-code arithmetic is BIT-IDENTICAL to R0 (which passed
// with absmax 3.8e-6): pairwise-8 x_sq with fp-contract off, sequential
// d-ascending fp32 FMA dot chain, dist = (x_sq - 2*dot) + e_sq. Chunk results
// merged in ascending-chunk order with strict '<' == np first-occurrence argmin.

#define KCODES 1024
#define DDIM   64
#define NPIX   65536        // B*H*W
#define QELEMS 4194304      // B*C*H*W
#define IDX_OFF (1 + QELEMS)
#define NWAVE  8            // waves per block = K chunks
#define CHUNK  (KCODES / NWAVE)   // 128 codes per wave

// ---------------- e_sq precompute: replicate np.sum(e*e, axis=1) pairwise-8 ----------------
__global__ void __launch_bounds__(256) esq_kernel(const float* __restrict__ e,
                                                  float* __restrict__ esq) {
    int k = blockIdx.x * 256 + threadIdx.x;
    if (k >= KCODES) return;
    {
#pragma clang fp contract(off)
        const float* row = e + k * DDIM;
        float r[8];
#pragma unroll
        for (int j = 0; j < 8; ++j) r[j] = row[j] * row[j];
#pragma unroll
        for (int i = 1; i < 8; ++i) {
#pragma unroll
            for (int j = 0; j < 8; ++j) {
                float v = row[i * 8 + j];
                r[j] += v * v;
            }
        }
        esq[k] = ((r[0] + r[1]) + (r[2] + r[3])) + ((r[4] + r[5]) + (r[6] + r[7]));
    }
}

// ---------------- main distance + argmin kernel (K-split) ----------------
// Block = 512 threads = 8 waves. Wave w, lane l: pixel = blockIdx*64 + l,
// codes [w*128, w*128+128). e-row loads wave-uniform -> s_load broadcast.
__global__ void __launch_bounds__(512) argmin_kernel(const float* __restrict__ x,
                                                     const float* __restrict__ e,
                                                     const float* __restrict__ esq,
                                                     int* __restrict__ idx_out,
                                                     float* __restrict__ out) {
    const int w = threadIdx.x >> 6;          // wave id = chunk id
    const int l = threadIdx.x & 63;          // lane = pixel within group
    const int i = blockIdx.x * 64 + l;       // pixel id
    const int b = i >> 10;
    const int p = i & 1023;

    // x[b][d][p], d-stride = 1024 floats; lanes -> 64 consecutive p (coalesced)
    const float* xb = x + (size_t)b * 65536 + p;
    float xr[DDIM];
#pragma unroll
    for (int d = 0; d < DDIM; ++d) xr[d] = xb[(size_t)d * 1024];

    // x_sq: EXACT replication of numpy pairwise-8 (rounded products, no fp contraction)
    float xsq;
    {
#pragma clang fp contract(off)
        float r[8];
#pragma unroll
        for (int j = 0; j < 8; ++j) r[j] = xr[j] * xr[j];
#pragma unroll
        for (int ii = 1; ii < 8; ++ii) {
#pragma unroll
            for (int j = 0; j < 8; ++j) {
                float v = xr[ii * 8 + j];
                r[j] += v * v;
            }
        }
        xsq = ((r[0] + r[1]) + (r[2] + r[3])) + ((r[4] + r[5]) + (r[6] + r[7]));
    }

    float best = 3.4e38f;
    int bidx = 0;
    const int kend = w * CHUNK + CHUNK;
    for (int k = w * CHUNK; k < kend; k += 4) {
        const float* e0 = e + (size_t)k * DDIM;
        float d0 = 0.f, d1 = 0.f, d2 = 0.f, d3 = 0.f;
        // BLAS-style: sequential FMA chain over d ascending (one chain per code)
#pragma unroll
        for (int d = 0; d < DDIM; ++d) {
            float xv = xr[d];
            d0 = __builtin_fmaf(xv, e0[d], d0);
            d1 = __builtin_fmaf(xv, e0[64 + d], d1);
            d2 = __builtin_fmaf(xv, e0[128 + d], d2);
            d3 = __builtin_fmaf(xv, e0[192 + d], d3);
        }
        // dist = (x_sq - 2*dot) + e_sq   (same association as np; /64 exact-monotone, skipped)
        float s0 = (xsq - 2.0f * d0) + esq[k + 0];
        float s1 = (xsq - 2.0f * d1) + esq[k + 1];
        float s2 = (xsq - 2.0f * d2) + esq[k + 2];
        float s3 = (xsq - 2.0f * d3) + esq[k + 3];
        // strict < , ascending k  => first-occurrence min within chunk
        if (s0 < best) { best = s0; bidx = k + 0; }
        if (s1 < best) { best = s1; bidx = k + 1; }
        if (s2 < best) { best = s2; bidx = k + 2; }
        if (s3 < best) { best = s3; bidx = k + 3; }
    }

    // merge the 8 chunk results: ascending chunk + strict '<' == global first-min
    __shared__ float sbest[NWAVE][64];
    __shared__ int   sidx[NWAVE][64];
    sbest[w][l] = best;
    sidx[w][l] = bidx;
    __syncthreads();
    if (threadIdx.x < 64) {
        float bb = sbest[0][l];
        int bi = sidx[0][l];
#pragma unroll
        for (int c = 1; c < NWAVE; ++c) {
            float v = sbest[c][l];
            if (v < bb) { bb = v; bi = sidx[c][l]; }
        }
        idx_out[i] = bi;
        out[IDX_OFF + i] = (float)bi;   // harness reads d_out as float32
    }
}

// ---------------- gather + transpose + per-block loss partials ----------------
// block = one (b,d) plane of 1024 pixels; coalesced read/write.
__global__ void __launch_bounds__(256) gather_kernel(const float* __restrict__ x,
                                                     const float* __restrict__ e,
                                                     const int* __restrict__ idx,
                                                     float* __restrict__ out,
                                                     float* __restrict__ partial) {
    const int bd = blockIdx.x;          // = b*64 + d
    const int b = bd >> 6;
    const int d = bd & 63;
    const size_t base = (size_t)bd * 1024;
    const int* idxb = idx + b * 1024;

    float acc = 0.f;
#pragma unroll
    for (int j = 0; j < 4; ++j) {
        int p = threadIdx.x + j * 256;
        int k = idxb[p];
        float ev = e[k * 64 + d];
        float xv = x[base + p];
        out[1 + base + p] = ev;         // quantized (straight-through == codebook value)
        float df = ev - xv;
        acc = __builtin_fmaf(df, df, acc);
    }
    __shared__ float sm[256];
    sm[threadIdx.x] = acc;
    __syncthreads();
    for (int s = 128; s > 0; s >>= 1) {
        if (threadIdx.x < s) sm[threadIdx.x] += sm[threadIdx.x + s];
        __syncthreads();
    }
    if (threadIdx.x == 0) partial[bd] = sm[0];
}

// ---------------- deterministic loss finalize ----------------
__global__ void __launch_bounds__(256) loss_kernel(const float* __restrict__ partial,
                                                   float* __restrict__ out) {
    float acc = 0.f;
    for (int i = threadIdx.x; i < 4096; i += 256) acc += partial[i];
    __shared__ float sm[256];
    sm[threadIdx.x] = acc;
    __syncthreads();
    for (int s = 128; s > 0; s >>= 1) {
        if (threadIdx.x < s) sm[threadIdx.x] += sm[threadIdx.x + s];
        __syncthreads();
    }
    // loss = q_latent + 0.25*e_latent = 1.25 * mean(diff^2)
    if (threadIdx.x == 0) out[0] = sm[0] * (1.25f / 4194304.f);
}

extern "C" void kernel_launch(void* const* d_in, const int* in_sizes, int n_in,
                              void* d_out, int out_size, void* d_ws, size_t ws_size,
                              hipStream_t stream) {
    const float* x = (const float*)d_in[0];   // [64,64,32,32]
    const float* e = (const float*)d_in[1];   // [1024,64]
    float* out = (float*)d_out;

    // ws: [0,4KB) e_sq | [4KB, 4KB+256KB) idx int32 | then 16KB partials
    float* esq = (float*)d_ws;
    int* idx = (int*)((char*)d_ws + 4096);
    float* partial = (float*)((char*)d_ws + 4096 + NPIX * 4);

    esq_kernel<<<4, 256, 0, stream>>>(e, esq);
    argmin_kernel<<<NPIX / 64, 512, 0, stream>>>(x, e, esq, idx, out);
    gather_kernel<<<4096, 256, 0, stream>>>(x, e, idx, out, partial);
    loss_kernel<<<1, 256, 0, stream>>>(partial, out);
}

// Round 3
// 189.851 us; speedup vs baseline: 2.5870x; 2.5870x over previous
//
#include <hip/hip_runtime.h>

// VQ-VAE VectorQuantizer forward, fp32, MI355X.
// B=64, C=D=64, H=W=32 -> N=65536 pixels, K=1024 codes.
// Outputs (flat concat): [0] loss, [1..4194305) quantized BCHW, [4194305..) indices (as float)
//
// R2: K-split argmin with UNIFORM chunk id via readfirstlane.
// R1 lesson: w = threadIdx.x>>6 is divergent to the compiler -> e loads became
// per-lane global_load (1:1 VMEM:FMA) -> VALU throttled at 26%. readfirstlane
// moves the chunk id to an SGPR so e/esq loads scalarize to s_load broadcasts
// (R0 behavior, SGPR=112) while keeping R1's 8x wave count.
// Per-code arithmetic BIT-IDENTICAL to R0/R1 (passed, absmax 3.8e-6):
// pairwise-8 x_sq (fp-contract off), sequential d-ascending fp32 FMA dot,
// dist = (x_sq - 2*dot) + e_sq, strict-< ascending-k argmin.

#define KCODES 1024
#define DDIM   64
#define NPIX   65536        // B*H*W
#define QELEMS 4194304      // B*C*H*W
#define IDX_OFF (1 + QELEMS)
#define NWAVE  8            // waves per block = K chunks
#define CHUNK  (KCODES / NWAVE)   // 128 codes per wave

// ---------------- e_sq precompute: replicate np.sum(e*e, axis=1) pairwise-8 ----------------
__global__ void __launch_bounds__(256) esq_kernel(const float* __restrict__ e,
                                                  float* __restrict__ esq) {
    int k = blockIdx.x * 256 + threadIdx.x;
    if (k >= KCODES) return;
    {
#pragma clang fp contract(off)
        const float* row = e + k * DDIM;
        float r[8];
#pragma unroll
        for (int j = 0; j < 8; ++j) r[j] = row[j] * row[j];
#pragma unroll
        for (int i = 1; i < 8; ++i) {
#pragma unroll
            for (int j = 0; j < 8; ++j) {
                float v = row[i * 8 + j];
                r[j] += v * v;
            }
        }
        esq[k] = ((r[0] + r[1]) + (r[2] + r[3])) + ((r[4] + r[5]) + (r[6] + r[7]));
    }
}

// ---------------- main distance + argmin kernel (K-split, uniform chunk) ----------------
// Block = 512 threads = 8 waves. Wave w, lane l: pixel = blockIdx*64 + l,
// codes [w*128, w*128+128). Chunk id forced into SGPR -> e loads are s_load.
__global__ void __launch_bounds__(512) argmin_kernel(const float* __restrict__ x,
                                                     const float* __restrict__ e,
                                                     const float* __restrict__ esq,
                                                     int* __restrict__ idx_out,
                                                     float* __restrict__ out) {
    // wave id: identical on all lanes; readfirstlane makes it compiler-provably
    // uniform (SGPR) so the k-loop bounds and e pointers scalarize.
    const int w = __builtin_amdgcn_readfirstlane(threadIdx.x >> 6);
    const int l = threadIdx.x & 63;          // lane = pixel within group
    const int i = blockIdx.x * 64 + l;       // pixel id
    const int b = i >> 10;
    const int p = i & 1023;

    // x[b][d][p], d-stride = 1024 floats; lanes -> 64 consecutive p (coalesced)
    const float* xb = x + (size_t)b * 65536 + p;
    float xr[DDIM];
#pragma unroll
    for (int d = 0; d < DDIM; ++d) xr[d] = xb[(size_t)d * 1024];

    // x_sq: EXACT replication of numpy pairwise-8 (rounded products, no fp contraction)
    float xsq;
    {
#pragma clang fp contract(off)
        float r[8];
#pragma unroll
        for (int j = 0; j < 8; ++j) r[j] = xr[j] * xr[j];
#pragma unroll
        for (int ii = 1; ii < 8; ++ii) {
#pragma unroll
            for (int j = 0; j < 8; ++j) {
                float v = xr[ii * 8 + j];
                r[j] += v * v;
            }
        }
        xsq = ((r[0] + r[1]) + (r[2] + r[3])) + ((r[4] + r[5]) + (r[6] + r[7]));
    }

    float best = 3.4e38f;
    int bidx = 0;
    const int kbeg = w * CHUNK;              // uniform (SGPR)
    for (int k = kbeg; k < kbeg + CHUNK; k += 4) {
        const float* e0 = e + (size_t)k * DDIM;   // uniform -> s_load
        float d0 = 0.f, d1 = 0.f, d2 = 0.f, d3 = 0.f;
        // BLAS-style: sequential FMA chain over d ascending (one chain per code)
#pragma unroll
        for (int d = 0; d < DDIM; ++d) {
            float xv = xr[d];
            d0 = __builtin_fmaf(xv, e0[d], d0);
            d1 = __builtin_fmaf(xv, e0[64 + d], d1);
            d2 = __builtin_fmaf(xv, e0[128 + d], d2);
            d3 = __builtin_fmaf(xv, e0[192 + d], d3);
        }
        // dist = (x_sq - 2*dot) + e_sq   (same association as np; 2*d exact, /64 monotone)
        float s0 = (xsq - 2.0f * d0) + esq[k + 0];
        float s1 = (xsq - 2.0f * d1) + esq[k + 1];
        float s2 = (xsq - 2.0f * d2) + esq[k + 2];
        float s3 = (xsq - 2.0f * d3) + esq[k + 3];
        // strict < , ascending k  => first-occurrence min within chunk
        if (s0 < best) { best = s0; bidx = k + 0; }
        if (s1 < best) { best = s1; bidx = k + 1; }
        if (s2 < best) { best = s2; bidx = k + 2; }
        if (s3 < best) { best = s3; bidx = k + 3; }
    }

    // merge the 8 chunk results: ascending chunk + strict '<' == global first-min
    __shared__ float sbest[NWAVE][64];
    __shared__ int   sidx[NWAVE][64];
    sbest[w][l] = best;
    sidx[w][l] = bidx;
    __syncthreads();
    if (threadIdx.x < 64) {
        float bb = sbest[0][l];
        int bi = sidx[0][l];
#pragma unroll
        for (int c = 1; c < NWAVE; ++c) {
            float v = sbest[c][l];
            if (v < bb) { bb = v; bi = sidx[c][l]; }
        }
        idx_out[i] = bi;
        out[IDX_OFF + i] = (float)bi;   // harness reads d_out as float32
    }
}

// ---------------- gather + transpose + per-block loss partials ----------------
// block = one (b,d) plane of 1024 pixels; coalesced read/write.
__global__ void __launch_bounds__(256) gather_kernel(const float* __restrict__ x,
                                                     const float* __restrict__ e,
                                                     const int* __restrict__ idx,
                                                     float* __restrict__ out,
                                                     float* __restrict__ partial) {
    const int bd = blockIdx.x;          // = b*64 + d
    const int b = bd >> 6;
    const int d = bd & 63;
    const size_t base = (size_t)bd * 1024;
    const int* idxb = idx + b * 1024;

    float acc = 0.f;
#pragma unroll
    for (int j = 0; j < 4; ++j) {
        int p = threadIdx.x + j * 256;
        int k = idxb[p];
        float ev = e[k * 64 + d];
        float xv = x[base + p];
        out[1 + base + p] = ev;         // quantized (straight-through == codebook value)
        float df = ev - xv;
        acc = __builtin_fmaf(df, df, acc);
    }
    __shared__ float sm[256];
    sm[threadIdx.x] = acc;
    __syncthreads();
    for (int s = 128; s > 0; s >>= 1) {
        if (threadIdx.x < s) sm[threadIdx.x] += sm[threadIdx.x + s];
        __syncthreads();
    }
    if (threadIdx.x == 0) partial[bd] = sm[0];
}

// ---------------- deterministic loss finalize ----------------
__global__ void __launch_bounds__(256) loss_kernel(const float* __restrict__ partial,
                                                   float* __restrict__ out) {
    float acc = 0.f;
    for (int i = threadIdx.x; i < 4096; i += 256) acc += partial[i];
    __shared__ float sm[256];
    sm[threadIdx.x] = acc;
    __syncthreads();
    for (int s = 128; s > 0; s >>= 1) {
        if (threadIdx.x < s) sm[threadIdx.x] += sm[threadIdx.x + s];
        __syncthreads();
    }
    // loss = q_latent + 0.25*e_latent = 1.25 * mean(diff^2)
    if (threadIdx.x == 0) out[0] = sm[0] * (1.25f / 4194304.f);
}

extern "C" void kernel_launch(void* const* d_in, const int* in_sizes, int n_in,
                              void* d_out, int out_size, void* d_ws, size_t ws_size,
                              hipStream_t stream) {
    const float* x = (const float*)d_in[0];   // [64,64,32,32]
    const float* e = (const float*)d_in[1];   // [1024,64]
    float* out = (float*)d_out;

    // ws: [0,4KB) e_sq | [4KB, 4KB+256KB) idx int32 | then 16KB partials
    float* esq = (float*)d_ws;
    int* idx = (int*)((char*)d_ws + 4096);
    float* partial = (float*)((char*)d_ws + 4096 + NPIX * 4);

    esq_kernel<<<4, 256, 0, stream>>>(e, esq);
    argmin_kernel<<<NPIX / 64, 512, 0, stream>>>(x, e, esq, idx, out);
    gather_kernel<<<4096, 256, 0, stream>>>(x, e, idx, out, partial);
    loss_kernel<<<1, 256, 0, stream>>>(partial, out);
}

// Round 4
// 179.769 us; speedup vs baseline: 2.7321x; 1.0561x over previous
//
#include <hip/hip_runtime.h>

// VQ-VAE VectorQuantizer forward, fp32, MI355X.
// B=64, C=D=64, H=W=32 -> N=65536 pixels, K=1024 codes.
// Outputs (flat concat): [0] loss, [1..4194305) quantized BCHW, [4194305..) indices (as float)
//
// R3: launch_bounds(512,4) -> 128-VGPR budget so xr[64] stays register-resident
// (R2 had VGPR_Count=44 -> x rematerialized + no s_load prefetch headroom ->
// ~1100 stall cycles per k-group). k-loop unrolled to 8 codes/iter = two
// independent 4-chain sub-blocks so two s_load batches pipeline.
// Per-code arithmetic BIT-IDENTICAL to R0-R2 (passed, absmax 3.8e-6):
// pairwise-8 x_sq (fp-contract off), sequential d-ascending fp32 FMA dot,
// dist = (x_sq - 2*dot) + e_sq, strict-< ascending-k argmin, ascending-chunk merge.

#define KCODES 1024
#define DDIM   64
#define NPIX   65536        // B*H*W
#define QELEMS 4194304      // B*C*H*W
#define IDX_OFF (1 + QELEMS)
#define NWAVE  8            // waves per block = K chunks
#define CHUNK  (KCODES / NWAVE)   // 128 codes per wave

// ---------------- e_sq precompute: replicate np.sum(e*e, axis=1) pairwise-8 ----------------
__global__ void __launch_bounds__(256) esq_kernel(const float* __restrict__ e,
                                                  float* __restrict__ esq) {
    int k = blockIdx.x * 256 + threadIdx.x;
    if (k >= KCODES) return;
    {
#pragma clang fp contract(off)
        const float* row = e + k * DDIM;
        float r[8];
#pragma unroll
        for (int j = 0; j < 8; ++j) r[j] = row[j] * row[j];
#pragma unroll
        for (int i = 1; i < 8; ++i) {
#pragma unroll
            for (int j = 0; j < 8; ++j) {
                float v = row[i * 8 + j];
                r[j] += v * v;
            }
        }
        esq[k] = ((r[0] + r[1]) + (r[2] + r[3])) + ((r[4] + r[5]) + (r[6] + r[7]));
    }
}

// ---------------- main distance + argmin kernel (K-split, uniform chunk) ----------------
// Block = 512 threads = 8 waves. Wave w, lane l: pixel = blockIdx*64 + l,
// codes [w*128, w*128+128). Chunk id in SGPR via readfirstlane -> e loads s_load.
// launch_bounds(512,4): 4 waves/EU floor -> <=128 VGPRs -> xr[64] resident.
__global__ void __launch_bounds__(512, 4) argmin_kernel(const float* __restrict__ x,
                                                        const float* __restrict__ e,
                                                        const float* __restrict__ esq,
                                                        int* __restrict__ idx_out,
                                                        float* __restrict__ out) {
    const int w = __builtin_amdgcn_readfirstlane(threadIdx.x >> 6);
    const int l = threadIdx.x & 63;          // lane = pixel within group
    const int i = blockIdx.x * 64 + l;       // pixel id
    const int b = i >> 10;
    const int p = i & 1023;

    // x[b][d][p], d-stride = 1024 floats; lanes -> 64 consecutive p (coalesced)
    const float* xb = x + (size_t)b * 65536 + p;
    float xr[DDIM];
#pragma unroll
    for (int d = 0; d < DDIM; ++d) xr[d] = xb[(size_t)d * 1024];

    // x_sq: EXACT replication of numpy pairwise-8 (rounded products, no fp contraction)
    float xsq;
    {
#pragma clang fp contract(off)
        float r[8];
#pragma unroll
        for (int j = 0; j < 8; ++j) r[j] = xr[j] * xr[j];
#pragma unroll
        for (int ii = 1; ii < 8; ++ii) {
#pragma unroll
            for (int j = 0; j < 8; ++j) {
                float v = xr[ii * 8 + j];
                r[j] += v * v;
            }
        }
        xsq = ((r[0] + r[1]) + (r[2] + r[3])) + ((r[4] + r[5]) + (r[6] + r[7]));
    }

    float best = 3.4e38f;
    int bidx = 0;
    const int kbeg = w * CHUNK;              // uniform (SGPR)
    for (int k = kbeg; k < kbeg + CHUNK; k += 8) {
        const float* e0 = e + (size_t)k * DDIM;   // uniform -> s_load
        // two independent 4-chain sub-blocks -> two s_load batch streams in flight
        float d0 = 0.f, d1 = 0.f, d2 = 0.f, d3 = 0.f;
        float d4 = 0.f, d5 = 0.f, d6 = 0.f, d7 = 0.f;
#pragma unroll
        for (int d = 0; d < DDIM; ++d) {
            float xv = xr[d];
            d0 = __builtin_fmaf(xv, e0[d], d0);
            d1 = __builtin_fmaf(xv, e0[64 + d], d1);
            d2 = __builtin_fmaf(xv, e0[128 + d], d2);
            d3 = __builtin_fmaf(xv, e0[192 + d], d3);
            d4 = __builtin_fmaf(xv, e0[256 + d], d4);
            d5 = __builtin_fmaf(xv, e0[320 + d], d5);
            d6 = __builtin_fmaf(xv, e0[384 + d], d6);
            d7 = __builtin_fmaf(xv, e0[448 + d], d7);
        }
        // dist = (x_sq - 2*dot) + e_sq   (same association as np; /64 exact-monotone, skipped)
        float s0 = (xsq - 2.0f * d0) + esq[k + 0];
        float s1 = (xsq - 2.0f * d1) + esq[k + 1];
        float s2 = (xsq - 2.0f * d2) + esq[k + 2];
        float s3 = (xsq - 2.0f * d3) + esq[k + 3];
        float s4 = (xsq - 2.0f * d4) + esq[k + 4];
        float s5 = (xsq - 2.0f * d5) + esq[k + 5];
        float s6 = (xsq - 2.0f * d6) + esq[k + 6];
        float s7 = (xsq - 2.0f * d7) + esq[k + 7];
        // strict < , ascending k  => first-occurrence min within chunk
        if (s0 < best) { best = s0; bidx = k + 0; }
        if (s1 < best) { best = s1; bidx = k + 1; }
        if (s2 < best) { best = s2; bidx = k + 2; }
        if (s3 < best) { best = s3; bidx = k + 3; }
        if (s4 < best) { best = s4; bidx = k + 4; }
        if (s5 < best) { best = s5; bidx = k + 5; }
        if (s6 < best) { best = s6; bidx = k + 6; }
        if (s7 < best) { best = s7; bidx = k + 7; }
    }

    // merge the 8 chunk results: ascending chunk + strict '<' == global first-min
    __shared__ float sbest[NWAVE][64];
    __shared__ int   sidx[NWAVE][64];
    sbest[w][l] = best;
    sidx[w][l] = bidx;
    __syncthreads();
    if (threadIdx.x < 64) {
        float bb = sbest[0][l];
        int bi = sidx[0][l];
#pragma unroll
        for (int c = 1; c < NWAVE; ++c) {
            float v = sbest[c][l];
            if (v < bb) { bb = v; bi = sidx[c][l]; }
        }
        idx_out[i] = bi;
        out[IDX_OFF + i] = (float)bi;   // harness reads d_out as float32
    }
}

// ---------------- gather + transpose + per-block loss partials ----------------
// block = one (b,d) plane of 1024 pixels; coalesced read/write.
__global__ void __launch_bounds__(256) gather_kernel(const float* __restrict__ x,
                                                     const float* __restrict__ e,
                                                     const int* __restrict__ idx,
                                                     float* __restrict__ out,
                                                     float* __restrict__ partial) {
    const int bd = blockIdx.x;          // = b*64 + d
    const int b = bd >> 6;
    const int d = bd & 63;
    const size_t base = (size_t)bd * 1024;
    const int* idxb = idx + b * 1024;

    float acc = 0.f;
#pragma unroll
    for (int j = 0; j < 4; ++j) {
        int p = threadIdx.x + j * 256;
        int k = idxb[p];
        float ev = e[k * 64 + d];
        float xv = x[base + p];
        out[1 + base + p] = ev;         // quantized (straight-through == codebook value)
        float df = ev - xv;
        acc = __builtin_fmaf(df, df, acc);
    }
    __shared__ float sm[256];
    sm[threadIdx.x] = acc;
    __syncthreads();
    for (int s = 128; s > 0; s >>= 1) {
        if (threadIdx.x < s) sm[threadIdx.x] += sm[threadIdx.x + s];
        __syncthreads();
    }
    if (threadIdx.x == 0) partial[bd] = sm[0];
}

// ---------------- deterministic loss finalize ----------------
__global__ void __launch_bounds__(256) loss_kernel(const float* __restrict__ partial,
                                                   float* __restrict__ out) {
    float acc = 0.f;
    for (int i = threadIdx.x; i < 4096; i += 256) acc += partial[i];
    __shared__ float sm[256];
    sm[threadIdx.x] = acc;
    __syncthreads();
    for (int s = 128; s > 0; s >>= 1) {
        if (threadIdx.x < s) sm[threadIdx.x] += sm[threadIdx.x + s];
        __syncthreads();
    }
    // loss = q_latent + 0.25*e_latent = 1.25 * mean(diff^2)
    if (threadIdx.x == 0) out[0] = sm[0] * (1.25f / 4194304.f);
}

extern "C" void kernel_launch(void* const* d_in, const int* in_sizes, int n_in,
                              void* d_out, int out_size, void* d_ws, size_t ws_size,
                              hipStream_t stream) {
    const float* x = (const float*)d_in[0];   // [64,64,32,32]
    const float* e = (const float*)d_in[1];   // [1024,64]
    float* out = (float*)d_out;

    // ws: [0,4KB) e_sq | [4KB, 4KB+256KB) idx int32 | then 16KB partials
    float* esq = (float*)d_ws;
    int* idx = (int*)((char*)d_ws + 4096);
    float* partial = (float*)((char*)d_ws + 4096 + NPIX * 4);

    esq_kernel<<<4, 256, 0, stream>>>(e, esq);
    argmin_kernel<<<NPIX / 64, 512, 0, stream>>>(x, e, esq, idx, out);
    gather_kernel<<<4096, 256, 0, stream>>>(x, e, idx, out, partial);
    loss_kernel<<<1, 256, 0, stream>>>(partial, out);
}

// Round 5
// 146.323 us; speedup vs baseline: 3.3566x; 1.2286x over previous
//
#include <hip/hip_runtime.h>

// VQ-VAE VectorQuantizer forward, fp32, MI355X.
// B=64, C=D=64, H=W=32 -> N=65536 pixels, K=1024 codes.
// Outputs (flat concat): [0] loss, [1..4194305) quantized BCHW, [4194305..) indices (as float)
//
// R5: 2 pixels/lane (halves scalar-path e traffic, the hypothesized bottleneck:
// 256MB of s_load streaming at ~few B/cyc/CU ~= the measured 168us) + asm
// keep-alive anchors so the compiler can't rematerialize xr (R3/R4 stuck at
// VGPR=44, reloading x per k-group) + launch_bounds(512,2) for a 256-VGPR cap
// + '#pragma unroll 1' on the k-loop to keep the body I$-resident.
// Per-code arithmetic BIT-IDENTICAL to R0-R4 (passed, absmax 3.8e-6):
// pairwise-8 x_sq (fp-contract off), sequential d-ascending fp32 FMA dot,
// dist = (x_sq - 2*dot) + e_sq, strict-< ascending-k argmin, ascending-chunk merge.

#define KCODES 1024
#define DDIM   64
#define NPIX   65536        // B*H*W
#define QELEMS 4194304      // B*C*H*W
#define IDX_OFF (1 + QELEMS)
#define NWAVE  8            // waves per block = K chunks
#define CHUNK  (KCODES / NWAVE)   // 128 codes per wave
#define PXB    128          // pixels per block (2 per lane)

// ---------------- e_sq precompute: replicate np.sum(e*e, axis=1) pairwise-8 ----------------
__global__ void __launch_bounds__(256) esq_kernel(const float* __restrict__ e,
                                                  float* __restrict__ esq) {
    int k = blockIdx.x * 256 + threadIdx.x;
    if (k >= KCODES) return;
    {
#pragma clang fp contract(off)
        const float* row = e + k * DDIM;
        float r[8];
#pragma unroll
        for (int j = 0; j < 8; ++j) r[j] = row[j] * row[j];
#pragma unroll
        for (int i = 1; i < 8; ++i) {
#pragma unroll
            for (int j = 0; j < 8; ++j) {
                float v = row[i * 8 + j];
                r[j] += v * v;
            }
        }
        esq[k] = ((r[0] + r[1]) + (r[2] + r[3])) + ((r[4] + r[5]) + (r[6] + r[7]));
    }
}

// x_sq helper: EXACT replication of numpy pairwise-8 (no fp contraction)
__device__ __forceinline__ float xsq_pairwise8(const float* xr) {
#pragma clang fp contract(off)
    float r[8];
#pragma unroll
    for (int j = 0; j < 8; ++j) r[j] = xr[j] * xr[j];
#pragma unroll
    for (int ii = 1; ii < 8; ++ii) {
#pragma unroll
        for (int j = 0; j < 8; ++j) {
            float v = xr[ii * 8 + j];
            r[j] += v * v;
        }
    }
    return ((r[0] + r[1]) + (r[2] + r[3])) + ((r[4] + r[5]) + (r[6] + r[7]));
}

// ---------------- main distance + argmin kernel (K-split, 2 px/lane) ----------------
// Block = 512 threads = 8 waves. Wave w handles codes [w*128, w*128+128) for the
// block's 128 pixels: lane l owns pixels blk*128+l and blk*128+l+64.
// Chunk id in SGPR via readfirstlane -> e/esq loads are s_load broadcasts.
__global__ void __launch_bounds__(512, 2) argmin_kernel(const float* __restrict__ x,
                                                        const float* __restrict__ e,
                                                        const float* __restrict__ esq,
                                                        int* __restrict__ idx_out,
                                                        float* __restrict__ out) {
    const int w = __builtin_amdgcn_readfirstlane(threadIdx.x >> 6);
    const int l = threadIdx.x & 63;
    const int i0 = blockIdx.x * PXB + l;     // first pixel
    // 128-aligned block within a 1024-pixel batch => same b for both pixels
    const int b = i0 >> 10;
    const int p0 = i0 & 1023;

    // x[b][d][p], d-stride = 1024 floats; lanes -> consecutive p (coalesced)
    const float* xb = x + (size_t)b * 65536 + p0;
    float xr0[DDIM], xr1[DDIM];
#pragma unroll
    for (int d = 0; d < DDIM; ++d) xr0[d] = xb[(size_t)d * 1024];
#pragma unroll
    for (int d = 0; d < DDIM; ++d) xr1[d] = xb[(size_t)d * 1024 + 64];
    // keep-alive anchors: opaque asm defs prevent rematerialization/reload
#pragma unroll
    for (int d = 0; d < DDIM; ++d) { asm volatile("" : "+v"(xr0[d])); asm volatile("" : "+v"(xr1[d])); }

    const float xsq0 = xsq_pairwise8(xr0);
    const float xsq1 = xsq_pairwise8(xr1);

    float best0 = 3.4e38f, best1 = 3.4e38f;
    int bidx0 = 0, bidx1 = 0;
    const int kbeg = w * CHUNK;              // uniform (SGPR)
#pragma unroll 1
    for (int k = kbeg; k < kbeg + CHUNK; k += 8) {
        const float* e0 = e + (size_t)k * DDIM;   // uniform -> s_load
        float a0 = 0.f, a1 = 0.f, a2 = 0.f, a3 = 0.f, a4 = 0.f, a5 = 0.f, a6 = 0.f, a7 = 0.f;
        float c0 = 0.f, c1 = 0.f, c2 = 0.f, c3 = 0.f, c4 = 0.f, c5 = 0.f, c6 = 0.f, c7 = 0.f;
#pragma unroll
        for (int d = 0; d < DDIM; ++d) {
            const float xv0 = xr0[d];
            const float xv1 = xr1[d];
            const float e_0 = e0[d];
            const float e_1 = e0[64 + d];
            const float e_2 = e0[128 + d];
            const float e_3 = e0[192 + d];
            const float e_4 = e0[256 + d];
            const float e_5 = e0[320 + d];
            const float e_6 = e0[384 + d];
            const float e_7 = e0[448 + d];
            a0 = __builtin_fmaf(xv0, e_0, a0);  c0 = __builtin_fmaf(xv1, e_0, c0);
            a1 = __builtin_fmaf(xv0, e_1, a1);  c1 = __builtin_fmaf(xv1, e_1, c1);
            a2 = __builtin_fmaf(xv0, e_2, a2);  c2 = __builtin_fmaf(xv1, e_2, c2);
            a3 = __builtin_fmaf(xv0, e_3, a3);  c3 = __builtin_fmaf(xv1, e_3, c3);
            a4 = __builtin_fmaf(xv0, e_4, a4);  c4 = __builtin_fmaf(xv1, e_4, c4);
            a5 = __builtin_fmaf(xv0, e_5, a5);  c5 = __builtin_fmaf(xv1, e_5, c5);
            a6 = __builtin_fmaf(xv0, e_6, a6);  c6 = __builtin_fmaf(xv1, e_6, c6);
            a7 = __builtin_fmaf(xv0, e_7, a7);  c7 = __builtin_fmaf(xv1, e_7, c7);
        }
        // dist = (x_sq - 2*dot) + e_sq   (same association as np; /64 exact-monotone, skipped)
        const float q0 = esq[k + 0], q1 = esq[k + 1], q2 = esq[k + 2], q3 = esq[k + 3];
        const float q4 = esq[k + 4], q5 = esq[k + 5], q6 = esq[k + 6], q7 = esq[k + 7];
        float s0 = (xsq0 - 2.0f * a0) + q0;
        float s1 = (xsq0 - 2.0f * a1) + q1;
        float s2 = (xsq0 - 2.0f * a2) + q2;
        float s3 = (xsq0 - 2.0f * a3) + q3;
        float s4 = (xsq0 - 2.0f * a4) + q4;
        float s5 = (xsq0 - 2.0f * a5) + q5;
        float s6 = (xsq0 - 2.0f * a6) + q6;
        float s7 = (xsq0 - 2.0f * a7) + q7;
        float t0 = (xsq1 - 2.0f * c0) + q0;
        float t1 = (xsq1 - 2.0f * c1) + q1;
        float t2 = (xsq1 - 2.0f * c2) + q2;
        float t3 = (xsq1 - 2.0f * c3) + q3;
        float t4 = (xsq1 - 2.0f * c4) + q4;
        float t5 = (xsq1 - 2.0f * c5) + q5;
        float t6 = (xsq1 - 2.0f * c6) + q6;
        float t7 = (xsq1 - 2.0f * c7) + q7;
        // strict < , ascending k => first-occurrence min within chunk
        if (s0 < best0) { best0 = s0; bidx0 = k + 0; }
        if (s1 < best0) { best0 = s1; bidx0 = k + 1; }
        if (s2 < best0) { best0 = s2; bidx0 = k + 2; }
        if (s3 < best0) { best0 = s3; bidx0 = k + 3; }
        if (s4 < best0) { best0 = s4; bidx0 = k + 4; }
        if (s5 < best0) { best0 = s5; bidx0 = k + 5; }
        if (s6 < best0) { best0 = s6; bidx0 = k + 6; }
        if (s7 < best0) { best0 = s7; bidx0 = k + 7; }
        if (t0 < best1) { best1 = t0; bidx1 = k + 0; }
        if (t1 < best1) { best1 = t1; bidx1 = k + 1; }
        if (t2 < best1) { best1 = t2; bidx1 = k + 2; }
        if (t3 < best1) { best1 = t3; bidx1 = k + 3; }
        if (t4 < best1) { best1 = t4; bidx1 = k + 4; }
        if (t5 < best1) { best1 = t5; bidx1 = k + 5; }
        if (t6 < best1) { best1 = t6; bidx1 = k + 6; }
        if (t7 < best1) { best1 = t7; bidx1 = k + 7; }
    }

    // merge the 8 chunk results: ascending chunk + strict '<' == global first-min
    __shared__ float sbest[NWAVE][PXB];
    __shared__ int   sidx[NWAVE][PXB];
    sbest[w][l] = best0;        sbest[w][l + 64] = best1;
    sidx[w][l] = bidx0;         sidx[w][l + 64] = bidx1;
    __syncthreads();
    if (threadIdx.x < PXB) {
        const int t = threadIdx.x;
        float bb = sbest[0][t];
        int bi = sidx[0][t];
#pragma unroll
        for (int c = 1; c < NWAVE; ++c) {
            float v = sbest[c][t];
            if (v < bb) { bb = v; bi = sidx[c][t]; }
        }
        const int gi = blockIdx.x * PXB + t;
        idx_out[gi] = bi;
        out[IDX_OFF + gi] = (float)bi;   // harness reads d_out as float32
    }
}

// ---------------- gather + transpose + per-block loss partials ----------------
// block = one (b,d) plane of 1024 pixels; coalesced read/write.
__global__ void __launch_bounds__(256) gather_kernel(const float* __restrict__ x,
                                                     const float* __restrict__ e,
                                                     const int* __restrict__ idx,
                                                     float* __restrict__ out,
                                                     float* __restrict__ partial) {
    const int bd = blockIdx.x;          // = b*64 + d
    const int b = bd >> 6;
    const int d = bd & 63;
    const size_t base = (size_t)bd * 1024;
    const int* idxb = idx + b * 1024;

    float acc = 0.f;
#pragma unroll
    for (int j = 0; j < 4; ++j) {
        int p = threadIdx.x + j * 256;
        int k = idxb[p];
        float ev = e[k * 64 + d];
        float xv = x[base + p];
        out[1 + base + p] = ev;         // quantized (straight-through == codebook value)
        float df = ev - xv;
        acc = __builtin_fmaf(df, df, acc);
    }
    __shared__ float sm[256];
    sm[threadIdx.x] = acc;
    __syncthreads();
    for (int s = 128; s > 0; s >>= 1) {
        if (threadIdx.x < s) sm[threadIdx.x] += sm[threadIdx.x + s];
        __syncthreads();
    }
    if (threadIdx.x == 0) partial[bd] = sm[0];
}

// ---------------- deterministic loss finalize ----------------
__global__ void __launch_bounds__(256) loss_kernel(const float* __restrict__ partial,
                                                   float* __restrict__ out) {
    float acc = 0.f;
    for (int i = threadIdx.x; i < 4096; i += 256) acc += partial[i];
    __shared__ float sm[256];
    sm[threadIdx.x] = acc;
    __syncthreads();
    for (int s = 128; s > 0; s >>= 1) {
        if (threadIdx.x < s) sm[threadIdx.x] += sm[threadIdx.x + s];
        __syncthreads();
    }
    // loss = q_latent + 0.25*e_latent = 1.25 * mean(diff^2)
    if (threadIdx.x == 0) out[0] = sm[0] * (1.25f / 4194304.f);
}

extern "C" void kernel_launch(void* const* d_in, const int* in_sizes, int n_in,
                              void* d_out, int out_size, void* d_ws, size_t ws_size,
                              hipStream_t stream) {
    const float* x = (const float*)d_in[0];   // [64,64,32,32]
    const float* e = (const float*)d_in[1];   // [1024,64]
    float* out = (float*)d_out;

    // ws: [0,4KB) e_sq | [4KB, 4KB+256KB) idx int32 | then 16KB partials
    float* esq = (float*)d_ws;
    int* idx = (int*)((char*)d_ws + 4096);
    float* partial = (float*)((char*)d_ws + 4096 + NPIX * 4);

    esq_kernel<<<4, 256, 0, stream>>>(e, esq);
    argmin_kernel<<<NPIX / PXB, 512, 0, stream>>>(x, e, esq, idx, out);
    gather_kernel<<<4096, 256, 0, stream>>>(x, e, idx, out, partial);
    loss_kernel<<<1, 256, 0, stream>>>(partial, out);
}